// Round 8
// baseline (122.451 us; speedup 1.0000x reference)
//
#include <hip/hip_runtime.h>
#include <math.h>

#define EPSF 1e-5f
#define SINKHORN_ITERS 20
#define C_DIM 4096
#define N_DIM 4

typedef __attribute__((ext_vector_type(4))) float fx4;

// ws layout (floats): [0..3]=sigmoid(H_pre), [4..7]=2*sigmoid(H_post),
// [8..23]=M row-major, [32 + b]=inv[b].  Written fully by pass A every call.

// Pass A: streaming read-only RMS reduce. One block per batch row b.
// Reads x once (256MB, plain/cacheable -> warms L3 for pass B), writes 4
// bytes per block. The barrier here is cheap: no store phase follows it.
// Block 0 / thread 0 additionally runs the serial 4x4 sinkhorn (~3.2k cycle
// chain) -> params. R4 lesson: only ONE thread in the whole grid pays this;
// its block finishes ~1.3us late, hidden inside pass A's ~35us wall.
__global__ __launch_bounds__(512, 8)
void pass_a(const float* __restrict__ x,
            const float* __restrict__ H_pre,
            const float* __restrict__ H_post,
            const float* __restrict__ H_res,
            float* __restrict__ ws) {
    const int b = blockIdx.x;
    const int t = threadIdx.x;
    const size_t base = (size_t)b * (N_DIM * C_DIM);
    const int c0 = t * 4;

    // sigmoid(H_pre) inline — 4 exps, trivial (p needed pre-reduce)
    const float p0 = 1.0f / (1.0f + __expf(-H_pre[0]));
    const float p1 = 1.0f / (1.0f + __expf(-H_pre[1]));
    const float p2 = 1.0f / (1.0f + __expf(-H_pre[2]));
    const float p3 = 1.0f / (1.0f + __expf(-H_pre[3]));

    float ss = 0.0f;
    #pragma unroll
    for (int k = 0; k < 2; ++k) {
        fx4 x0 = *reinterpret_cast<const fx4*>(x + base + 0 * C_DIM + k * 2048 + c0);
        fx4 x1 = *reinterpret_cast<const fx4*>(x + base + 1 * C_DIM + k * 2048 + c0);
        fx4 x2 = *reinterpret_cast<const fx4*>(x + base + 2 * C_DIM + k * 2048 + c0);
        fx4 x3 = *reinterpret_cast<const fx4*>(x + base + 3 * C_DIM + k * 2048 + c0);
        fx4 a = p0 * x0 + p1 * x1 + p2 * x2 + p3 * x3;
        ss += a.x * a.x + a.y * a.y + a.z * a.z + a.w * a.w;
    }

    #pragma unroll
    for (int off = 32; off > 0; off >>= 1)
        ss += __shfl_down(ss, off, 64);
    __shared__ float sp[8];
    if ((t & 63) == 0) sp[t >> 6] = ss;
    __syncthreads();
    if (t == 0) {
        float tot = sp[0] + sp[1] + sp[2] + sp[3]
                  + sp[4] + sp[5] + sp[6] + sp[7];
        ws[32 + b] = 1.0f / sqrtf(tot * (1.0f / (float)C_DIM) + EPSF);
    }

    if (b == 0 && t == 0) {
        float M[4][4];
        #pragma unroll
        for (int i = 0; i < 4; ++i)
            #pragma unroll
            for (int j = 0; j < 4; ++j)
                M[i][j] = __expf(H_res[i * 4 + j]);
        for (int it = 0; it < SINKHORN_ITERS; ++it) {
            #pragma unroll
            for (int i = 0; i < 4; ++i) {       // row normalize (axis=1)
                float s = 1.0f / (M[i][0] + M[i][1] + M[i][2] + M[i][3] + EPSF);
                M[i][0] *= s; M[i][1] *= s; M[i][2] *= s; M[i][3] *= s;
            }
            #pragma unroll
            for (int j = 0; j < 4; ++j) {       // col normalize (axis=0)
                float s = 1.0f / (M[0][j] + M[1][j] + M[2][j] + M[3][j] + EPSF);
                M[0][j] *= s; M[1][j] *= s; M[2][j] *= s; M[3][j] *= s;
            }
        }
        ws[0] = p0; ws[1] = p1; ws[2] = p2; ws[3] = p3;
        #pragma unroll
        for (int i = 0; i < 4; ++i)
            ws[4 + i] = 2.0f / (1.0f + __expf(-H_post[i]));
        #pragma unroll
        for (int i = 0; i < 4; ++i)
            #pragma unroll
            for (int j = 0; j < 4; ++j)
                ws[8 + i * 4 + j] = M[i][j];
    }
}

// Pass B: pure stream — NO barrier, no LDS, no reduce. Reads x (L3-hot from
// pass A; plain loads), applies M/po/inv, NT-stores out (no-allocate: the
// 256MB output stream must not evict x from L3 — R5 counter evidence).
// Reversed block order: first touch what pass A cached last (anti-thrash
// for a stream exactly == L3 size).
__global__ __launch_bounds__(512, 8)
void pass_b(const float* __restrict__ x,
            const float* __restrict__ w,
            const float* __restrict__ ws,
            float* __restrict__ out) {
    const int b = (int)gridDim.x - 1 - (int)blockIdx.x;
    const int t = threadIdx.x;
    const size_t base = (size_t)b * (N_DIM * C_DIM);
    const int c0 = t * 4;

    // uniform -> scalar loads
    const float p0 = ws[0], p1 = ws[1], p2 = ws[2], p3 = ws[3];
    const float inv = ws[32 + b];

    #pragma unroll
    for (int k = 0; k < 2; ++k) {
        fx4 x0 = *reinterpret_cast<const fx4*>(x + base + 0 * C_DIM + k * 2048 + c0);
        fx4 x1 = *reinterpret_cast<const fx4*>(x + base + 1 * C_DIM + k * 2048 + c0);
        fx4 x2 = *reinterpret_cast<const fx4*>(x + base + 2 * C_DIM + k * 2048 + c0);
        fx4 x3 = *reinterpret_cast<const fx4*>(x + base + 3 * C_DIM + k * 2048 + c0);
        fx4 wv = *reinterpret_cast<const fx4*>(w + k * 2048 + c0);

        fx4 a = p0 * x0 + p1 * x1 + p2 * x2 + p3 * x3;
        fx4 nw = a * inv * wv;

        #pragma unroll
        for (int i = 0; i < 4; ++i) {
            const float m0 = ws[8 + i * 4 + 0];
            const float m1 = ws[8 + i * 4 + 1];
            const float m2 = ws[8 + i * 4 + 2];
            const float m3 = ws[8 + i * 4 + 3];
            const float po = ws[4 + i];
            fx4 o = m0 * x0 + m1 * x1 + m2 * x2 + m3 * x3 + po * nw;
            __builtin_nontemporal_store(
                o, reinterpret_cast<fx4*>(out + base + i * C_DIM + k * 2048 + c0));
        }
    }
}

extern "C" void kernel_launch(void* const* d_in, const int* in_sizes, int n_in,
                              void* d_out, int out_size, void* d_ws, size_t ws_size,
                              hipStream_t stream) {
    const float* x      = (const float*)d_in[0];
    const float* w      = (const float*)d_in[1];
    const float* H_pre  = (const float*)d_in[2];
    const float* H_post = (const float*)d_in[3];
    const float* H_res  = (const float*)d_in[4];
    float* out = (float*)d_out;
    float* ws  = (float*)d_ws;

    const int B = in_sizes[0] / (N_DIM * C_DIM);  // 4096

    pass_a<<<B, 512, 0, stream>>>(x, H_pre, H_post, H_res, ws);
    pass_b<<<B, 512, 0, stream>>>(x, w, ws, out);
}

// Round 9
// 102.797 us; speedup vs baseline: 1.1912x; 1.1912x over previous
//
#include <hip/hip_runtime.h>
#include <math.h>

#define EPSF 1e-5f
#define SINKHORN_ITERS 20
#define C_DIM 4096
#define N_DIM 4

typedef __attribute__((ext_vector_type(4))) float fx4;

// Kernel 1: tiny prep — sigmoids + sinkhorn on 4x4. params layout:
// [0..3] = sigmoid(H_pre), [4..7] = 2*sigmoid(H_post), [8..23] = M row-major.
// R4 lesson: this MUST stay a separate 1-thread kernel — folding it into the
// fused kernel made every wave pay a ~3.2k-cycle serial rcp chain (VALUBusy
// 97%, +50us).
__global__ void prep_kernel(const float* __restrict__ H_pre,
                            const float* __restrict__ H_post,
                            const float* __restrict__ H_res,
                            float* __restrict__ params) {
    if (threadIdx.x != 0 || blockIdx.x != 0) return;
    float M[4][4];
    for (int i = 0; i < 4; ++i)
        for (int j = 0; j < 4; ++j)
            M[i][j] = expf(H_res[i * 4 + j]);
    for (int it = 0; it < SINKHORN_ITERS; ++it) {
        for (int i = 0; i < 4; ++i) {       // row normalize (axis=1)
            float s = M[i][0] + M[i][1] + M[i][2] + M[i][3] + EPSF;
            M[i][0] /= s; M[i][1] /= s; M[i][2] /= s; M[i][3] /= s;
        }
        for (int j = 0; j < 4; ++j) {       // col normalize (axis=0)
            float s = M[0][j] + M[1][j] + M[2][j] + M[3][j] + EPSF;
            M[0][j] /= s; M[1][j] /= s; M[2][j] /= s; M[3][j] /= s;
        }
    }
    for (int i = 0; i < 4; ++i) {
        params[i]     = 1.0f / (1.0f + expf(-H_pre[i]));
        params[4 + i] = 2.0f / (1.0f + expf(-H_post[i]));
    }
    for (int i = 0; i < 4; ++i)
        for (int j = 0; j < 4; ++j)
            params[8 + i * 4 + j] = M[i][j];
}

// Kernel 2: one block (512 threads, 8 waves) per batch row b.
// Thread t owns columns {k*2048 + t*4 .. +3} for k=0..1 across all 4
// expansion rows. Single __syncthreads for the RMS reduce.
//
// Final structure (evidence this session):
// - single-pass (R8: two-pass double-read = +19%)
// - cacheable LOADS (R5: L3 retains x across replays, FETCH=131MB<256MB)
// - nontemporal STORES (output stream must not evict x from L3)
// - occupancy/schedule/pinning all null (R3/R6/R7) — kernel sits at
//   5.2 TB/s = 83% of the 6.29 TB/s copy ceiling, in the measured
//   single-pass-norm-class band (82-86%).
__global__ __launch_bounds__(512, 4)
void fused_kernel(const float* __restrict__ x,
                  const float* __restrict__ w,
                  const float* __restrict__ params,
                  float* __restrict__ out) {
    const int b = blockIdx.x;
    const int t = threadIdx.x;

    // uniform indices -> scalar (s_load) broadcast, zero VGPR cost
    const float p0 = params[0], p1 = params[1], p2 = params[2], p3 = params[3];

    const size_t base = (size_t)b * (N_DIM * C_DIM);
    const int c0 = t * 4;

    // Load x[b, i, k*2048 + c0 .. +3] — 8 float4 in flight, cacheable.
    fx4 xv[4][2];   // [row i][chunk k]
    #pragma unroll
    for (int i = 0; i < 4; ++i)
        #pragma unroll
        for (int k = 0; k < 2; ++k)
            xv[i][k] = *reinterpret_cast<const fx4*>(
                x + base + i * C_DIM + k * 2048 + c0);

    // w is L2-hot (16KB shared by all blocks) — issue pre-barrier too.
    fx4 wv[2];
    #pragma unroll
    for (int k = 0; k < 2; ++k)
        wv[k] = *reinterpret_cast<const fx4*>(w + k * 2048 + c0);

    // Pin: forbid rematerialization/load-sinking of the x-tile and w.
    #pragma unroll
    for (int i = 0; i < 4; ++i)
        #pragma unroll
        for (int k = 0; k < 2; ++k)
            asm volatile("" : "+v"(xv[i][k]));
    #pragma unroll
    for (int k = 0; k < 2; ++k)
        asm volatile("" : "+v"(wv[k]));

    // aggregate + sum of squares (agg recomputed later; only ss kept)
    float ss = 0.0f;
    #pragma unroll
    for (int k = 0; k < 2; ++k) {
        fx4 a = p0 * xv[0][k] + p1 * xv[1][k] + p2 * xv[2][k] + p3 * xv[3][k];
        ss += a.x * a.x + a.y * a.y + a.z * a.z + a.w * a.w;
    }

    // wave64 reduce -> 8 partials -> every thread sums them (one barrier)
    #pragma unroll
    for (int off = 32; off > 0; off >>= 1)
        ss += __shfl_down(ss, off, 64);
    __shared__ float sp[8];
    if ((t & 63) == 0) sp[t >> 6] = ss;
    __syncthreads();
    const float tot = sp[0] + sp[1] + sp[2] + sp[3]
                    + sp[4] + sp[5] + sp[6] + sp[7];
    const float inv = 1.0f / sqrtf(tot * (1.0f / (float)C_DIM) + EPSF);

    // output: out[b,i,c] = sum_j M[i][j] x[b,j,c] + post_i * (agg*inv*w)
    // pure register math + stores — no loads in this phase
    #pragma unroll
    for (int k = 0; k < 2; ++k) {
        fx4 a = p0 * xv[0][k] + p1 * xv[1][k] + p2 * xv[2][k] + p3 * xv[3][k];
        fx4 nw = a * inv * wv[k];
        #pragma unroll
        for (int i = 0; i < 4; ++i) {
            const float m0 = params[8 + i * 4 + 0];
            const float m1 = params[8 + i * 4 + 1];
            const float m2 = params[8 + i * 4 + 2];
            const float m3 = params[8 + i * 4 + 3];
            const float po = params[4 + i];
            fx4 o = m0 * xv[0][k] + m1 * xv[1][k] + m2 * xv[2][k] + m3 * xv[3][k]
                  + po * nw;
            __builtin_nontemporal_store(
                o, reinterpret_cast<fx4*>(out + base + i * C_DIM + k * 2048 + c0));
        }
    }
}

extern "C" void kernel_launch(void* const* d_in, const int* in_sizes, int n_in,
                              void* d_out, int out_size, void* d_ws, size_t ws_size,
                              hipStream_t stream) {
    const float* x      = (const float*)d_in[0];
    const float* w      = (const float*)d_in[1];
    const float* H_pre  = (const float*)d_in[2];
    const float* H_post = (const float*)d_in[3];
    const float* H_res  = (const float*)d_in[4];
    float* out    = (float*)d_out;
    float* params = (float*)d_ws;

    const int B = in_sizes[0] / (N_DIM * C_DIM);  // 4096

    prep_kernel<<<1, 64, 0, stream>>>(H_pre, H_post, H_res, params);
    fused_kernel<<<B, 512, 0, stream>>>(x, w, params, out);
}